// Round 3
// baseline (243.754 us; speedup 1.0000x reference)
//
#include <hip/hip_runtime.h>
#include <math.h>

#define S_LEN 2048
#define D_MODEL 512
#define NIMU 13
#define NPAR 9
#define NCOL 117                // 13*9
#define PCHUNK (S_LEN * NCOL)   // elements per K-partial chunk

static __device__ __forceinline__ float softplus_f(float x) {
    return (x > 20.f) ? x : log1pf(expf(x));
}

// ---------------- kernel 1: per-row layernorm stats ----------------
__global__ __launch_bounds__(256) void stats_kernel(const float* __restrict__ H,
                                                    float2* __restrict__ stats) {
    int wave = threadIdx.x >> 6;
    int lane = threadIdx.x & 63;
    int row = blockIdx.x * 4 + wave;
    if (row >= S_LEN) return;
    const float* hr = H + row * D_MODEL;
    float4 a = *(const float4*)&hr[lane * 4];
    float4 b = *(const float4*)&hr[256 + lane * 4];
    float sum = a.x + a.y + a.z + a.w + b.x + b.y + b.z + b.w;
    #pragma unroll
    for (int off = 32; off; off >>= 1) sum += __shfl_down(sum, off);
    sum = __shfl(sum, 0);
    float mu = sum * (1.f / 512.f);
    float vs = 0.f;
    vs += (a.x - mu) * (a.x - mu); vs += (a.y - mu) * (a.y - mu);
    vs += (a.z - mu) * (a.z - mu); vs += (a.w - mu) * (a.w - mu);
    vs += (b.x - mu) * (b.x - mu); vs += (b.y - mu) * (b.y - mu);
    vs += (b.z - mu) * (b.z - mu); vs += (b.w - mu) * (b.w - mu);
    #pragma unroll
    for (int off = 32; off; off >>= 1) vs += __shfl_down(vs, off);
    if (lane == 0) {
        float var = vs * (1.f / 512.f);
        float rstd = 1.0f / sqrtf(var + 1e-5f);
        stats[row] = make_float2(mu, rstd);
    }
}

// ---------------- kernel 2: projection GEMM ----------------
// grid (64 row-tiles of 32, 4 k-chunks of 128); block 256. Two 64-k passes per chunk.
// ATOMIC=0: plain stores of per-chunk partials; ATOMIC=1: atomicAdd fallback.
template <int ATOMIC>
__global__ __launch_bounds__(256) void proj_kernel(
    const float* __restrict__ H, const float2* __restrict__ stats,
    const float* __restrict__ lnw, const float* __restrict__ lnb,
    const float* __restrict__ W, float* __restrict__ Pout)
{
    __shared__ float Xs[32][64];     // [row][k]
    __shared__ float Ws[64][128];    // [k][col], zero-padded cols
    int tid = threadIdx.x;
    int row0 = blockIdx.x * 32;
    int k0 = blockIdx.y * 128;

    int cg = tid & 31;   // cols cg*4 .. cg*4+3
    int rr = tid >> 5;   // rows rr + 8*q
    float acc[4][4];
    #pragma unroll
    for (int q = 0; q < 4; ++q)
        for (int u = 0; u < 4; ++u) acc[q][u] = 0.f;

    for (int half = 0; half < 2; ++half) {
        int kh = k0 + half * 64;
        __syncthreads();   // protect LDS tiles from previous pass
        {   // stage normalized X tile: row tid>>3, k-octet (tid&7)*8
            int r = tid >> 3;
            int k = (tid & 7) * 8;
            int row = row0 + r;
            float2 st = stats[row];
            #pragma unroll
            for (int h = 0; h < 2; ++h) {
                float4 h4 = *(const float4*)&H[row * D_MODEL + kh + k + h * 4];
                float4 wv = *(const float4*)&lnw[kh + k + h * 4];
                float4 bv = *(const float4*)&lnb[kh + k + h * 4];
                Xs[r][k + h * 4 + 0] = (h4.x - st.x) * st.y * wv.x + bv.x;
                Xs[r][k + h * 4 + 1] = (h4.y - st.x) * st.y * wv.y + bv.y;
                Xs[r][k + h * 4 + 2] = (h4.z - st.x) * st.y * wv.z + bv.z;
                Xs[r][k + h * 4 + 3] = (h4.w - st.x) * st.y * wv.w + bv.w;
            }
        }
        #pragma unroll
        for (int it = 0; it < 32; ++it) {   // stage W (64 x 117 -> 64 x 128 padded)
            int idx = tid + it * 256;
            int k = idx >> 7;
            int c = idx & 127;
            Ws[k][c] = (c < NCOL) ? W[(kh + k) * NCOL + c] : 0.f;
        }
        __syncthreads();

        #pragma unroll 4
        for (int kb = 0; kb < 16; ++kb) {
            float4 w0 = *(float4*)&Ws[kb * 4 + 0][cg * 4];
            float4 w1 = *(float4*)&Ws[kb * 4 + 1][cg * 4];
            float4 w2 = *(float4*)&Ws[kb * 4 + 2][cg * 4];
            float4 w3 = *(float4*)&Ws[kb * 4 + 3][cg * 4];
            #pragma unroll
            for (int q = 0; q < 4; ++q) {
                float4 a = *(float4*)&Xs[rr + 8 * q][kb * 4];
                acc[q][0] = fmaf(a.w, w3.x, fmaf(a.z, w2.x, fmaf(a.y, w1.x, fmaf(a.x, w0.x, acc[q][0]))));
                acc[q][1] = fmaf(a.w, w3.y, fmaf(a.z, w2.y, fmaf(a.y, w1.y, fmaf(a.x, w0.y, acc[q][1]))));
                acc[q][2] = fmaf(a.w, w3.z, fmaf(a.z, w2.z, fmaf(a.y, w1.z, fmaf(a.x, w0.z, acc[q][2]))));
                acc[q][3] = fmaf(a.w, w3.w, fmaf(a.z, w2.w, fmaf(a.y, w1.w, fmaf(a.x, w0.w, acc[q][3]))));
            }
        }
    }

    float* Pk = ATOMIC ? Pout : (Pout + blockIdx.y * PCHUNK);
    #pragma unroll
    for (int q = 0; q < 4; ++q) {
        int row = row0 + rr + 8 * q;
        #pragma unroll
        for (int u = 0; u < 4; ++u) {
            int c = cg * 4 + u;
            if (c < NCOL) {
                if (ATOMIC) atomicAdd(&Pk[row * NCOL + c], acc[q][u]);
                else        Pk[row * NCOL + c] = acc[q][u];
            }
        }
    }
}

// ---------------- kernel 3: K-partial reduce + param transform + out init ----------------
// PARL/PARA: (c, -d/2*log2e, om/2pi, phi/2pi) for state init.
// ZLA: (zrL, ziL, zrA, ziA), z = e^{-d/2} * (cos om, sin om) — per-step rotation.
__global__ __launch_bounds__(256) void transform_kernel(
    const float* __restrict__ Pp, int nkc,
    const float* __restrict__ bias, const float* __restrict__ minp,
    float4* __restrict__ PARL, float4* __restrict__ PARA,
    float4* __restrict__ ZLA, float* __restrict__ out)
{
    int t = blockIdx.x * 256 + threadIdx.x;
    if (t >= S_LEN * NIMU) return;
    int s = t / NIMU;
    int m = t - s * NIMU;
    float pv[9];
    #pragma unroll
    for (int pp = 0; pp < 9; ++pp) {
        float v = bias[pp * NIMU + m];
        for (int kc = 0; kc < nkc; ++kc)
            v += Pp[kc * PCHUNK + s * NCOL + pp * NIMU + m];
        pv[pp] = v;
    }

    const float LOG2E = 1.4426950408889634f;
    const float INV2PI = 0.15915494309189535f;
    float zrL, ziL, zrA, ziA;
    {   // linear oscillator
        float d = sqrtf(pv[1] * pv[1] + 1e-5f);
        float kk = d * d * 0.25f + softplus_f(pv[0]);
        float om = 0.5f * sqrtf(fmaxf(4.f * kk - d * d, 0.f));
        PARL[m * S_LEN + s] = make_float4(pv[4], -0.5f * d * LOG2E, om * INV2PI, pv[6] * INV2PI);
        float e2 = __builtin_amdgcn_exp2f(-0.5f * d * LOG2E);
        float omr = om * INV2PI;
        zrL = e2 * __builtin_amdgcn_cosf(omr);
        ziL = e2 * __builtin_amdgcn_sinf(omr);
    }
    {   // angular oscillator
        float d = sqrtf(pv[3] * pv[3] + 1e-5f);
        float kk = d * d * 0.25f + softplus_f(pv[2]);
        float om = 0.5f * sqrtf(fmaxf(4.f * kk - d * d, 0.f));
        PARA[m * S_LEN + s] = make_float4(pv[5], -0.5f * d * LOG2E, om * INV2PI, pv[7] * INV2PI);
        float e2 = __builtin_amdgcn_exp2f(-0.5f * d * LOG2E);
        float omr = om * INV2PI;
        zrA = e2 * __builtin_amdgcn_cosf(omr);
        ziA = e2 * __builtin_amdgcn_sinf(omr);
    }
    ZLA[m * S_LEN + s] = make_float4(zrL, ziL, zrA, ziA);
    out[m * S_LEN + s] = minp[0] + pv[8];
}

// ---------------- kernel 4: triangular sum via complex-rotation recurrence ----------------
// block = (m, i-chunk ic of 128, dt-segment s of 128), 128 threads.
// thread tid: source i = 128*ic + tid; walks dt = 128*s + t, t in [0,128);
// dest j = i + dt = 128*(ic+s) + tid + t  ->  accJ[tid+t] (255 slots).
__global__ __launch_bounds__(128) void main_kernel(
    const float4* __restrict__ PARL, const float4* __restrict__ PARA,
    const float4* __restrict__ ZLA, float* __restrict__ out)
{
    __shared__ float accJ[256];
    int tid = threadIdx.x;
    int m = blockIdx.z;

    // decode blockIdx.x in [0,136) -> (ic, s) with s in [0, 16-ic)
    int p = blockIdx.x;
    int ic = 0, base = 0;
    #pragma unroll 1
    while (p >= base + (16 - ic)) { base += 16 - ic; ++ic; }
    int s = p - base;

    accJ[tid] = 0.f;
    accJ[tid + 128] = 0.f;
    __syncthreads();

    int i = ic * 128 + tid;              // source index
    float4 pl = PARL[m * S_LEN + i];
    float4 pa = PARA[m * S_LEN + i];
    float4 z  = ZLA[m * S_LEN + i];

    // init states at dt0 = 128*s
    float dtf = (float)(s * 128);
    float reL, imL, reA, imA;
    {
        float er = pl.x * __builtin_amdgcn_exp2f(dtf * pl.y);
        float r = fmaf(dtf, pl.z, pl.w); r -= floorf(r);
        reL = er * __builtin_amdgcn_cosf(r);
        imL = er * __builtin_amdgcn_sinf(r);
    }
    {
        float er = pa.x * __builtin_amdgcn_exp2f(dtf * pa.y);
        float r = fmaf(dtf, pa.z, pa.w); r -= floorf(r);
        reA = er * __builtin_amdgcn_cosf(r);
        imA = er * __builtin_amdgcn_sinf(r);
    }

    #pragma unroll 8
    for (int t = 0; t < 128; ++t) {
        atomicAdd(&accJ[tid + t], imL + imA);
        float nL = fmaf(reL, z.x, -(imL * z.y));
        imL = fmaf(reL, z.y, imL * z.x);
        reL = nL;
        float nA = fmaf(reA, z.z, -(imA * z.w));
        imA = fmaf(reA, z.w, imA * z.z);
        reA = nA;
    }
    __syncthreads();

    int jb = (ic + s) * 128;             // j for accJ slot 0
    #pragma unroll
    for (int k = tid; k < 255; k += 128) {
        int j = jb + k;
        if (j < S_LEN) atomicAdd(&out[m * S_LEN + j], accJ[k]);
    }
}

extern "C" void kernel_launch(void* const* d_in, const int* in_sizes, int n_in,
                              void* d_out, int out_size, void* d_ws, size_t ws_size,
                              hipStream_t stream)
{
    const float* H    = (const float*)d_in[0];
    const float* MINP = (const float*)d_in[1];
    const float* LNW  = (const float*)d_in[2];
    const float* LNB  = (const float*)d_in[3];
    const float* W    = (const float*)d_in[4];
    const float* B    = (const float*)d_in[5];
    float* out = (float*)d_out;

    const size_t PSZ   = (size_t)PCHUNK * sizeof(float);        // 958464
    const size_t STSZ  = S_LEN * sizeof(float2);                // 16384
    const size_t PARSZ = (size_t)S_LEN * NIMU * sizeof(float4); // 425984
    const size_t need4 = 4 * PSZ + STSZ + 3 * PARSZ;            // ~5.13 MB

    char* ws = (char*)d_ws;
    if (ws_size >= need4) {
        // fast path: 4 K-partials, no atomics in proj, no memset
        float*  Pp    = (float*)ws;
        float2* stats = (float2*)(ws + 4 * PSZ);
        float4* PARL  = (float4*)(ws + 4 * PSZ + STSZ);
        float4* PARA  = (float4*)(ws + 4 * PSZ + STSZ + PARSZ);
        float4* ZLA   = (float4*)(ws + 4 * PSZ + STSZ + 2 * PARSZ);
        stats_kernel<<<512, 256, 0, stream>>>(H, stats);
        proj_kernel<0><<<dim3(64, 4), 256, 0, stream>>>(H, stats, LNW, LNB, W, Pp);
        transform_kernel<<<(S_LEN * NIMU + 255) / 256, 256, 0, stream>>>(Pp, 4, B, MINP, PARL, PARA, ZLA, out);
        main_kernel<<<dim3(136, 1, NIMU), 128, 0, stream>>>(PARL, PARA, ZLA, out);
    } else {
        // fallback: atomic accumulation into single P
        float*  P     = (float*)ws;
        float2* stats = (float2*)(ws + PSZ);
        float4* PARL  = (float4*)(ws + PSZ + STSZ);
        float4* PARA  = (float4*)(ws + PSZ + STSZ + PARSZ);
        float4* ZLA   = (float4*)(ws + PSZ + STSZ + 2 * PARSZ);
        hipMemsetAsync(P, 0, PSZ, stream);
        stats_kernel<<<512, 256, 0, stream>>>(H, stats);
        proj_kernel<1><<<dim3(64, 4), 256, 0, stream>>>(H, stats, LNW, LNB, W, P);
        transform_kernel<<<(S_LEN * NIMU + 255) / 256, 256, 0, stream>>>(P, 1, B, MINP, PARL, PARA, ZLA, out);
        main_kernel<<<dim3(136, 1, NIMU), 128, 0, stream>>>(PARL, PARA, ZLA, out);
    }
}

// Round 4
// 112.152 us; speedup vs baseline: 2.1734x; 2.1734x over previous
//
#include <hip/hip_runtime.h>
#include <math.h>

#define S_LEN 2048
#define D_MODEL 512
#define NIMU 13
#define NCOL 117                 // 13*9
#define PCHUNK (S_LEN * NCOL)    // elements per K-partial chunk
#define WP_STRIDE 128            // padded W row stride

static __device__ __forceinline__ float softplus_f(float x) {
    return (x > 20.f) ? x : log1pf(expf(x));
}

// ---------------- kernel 1: per-row layernorm stats + W padding ----------------
// 512 blocks x 256. Block bx: rows 4bx..4bx+3 stats; also pads W row bx into Wp (stride 128).
__global__ __launch_bounds__(256) void stats_kernel(const float* __restrict__ H,
                                                    float2* __restrict__ stats,
                                                    const float* __restrict__ W,
                                                    float* __restrict__ Wp) {
    if (threadIdx.x < WP_STRIDE) {
        int c = threadIdx.x;
        Wp[blockIdx.x * WP_STRIDE + c] = (c < NCOL) ? W[blockIdx.x * NCOL + c] : 0.f;
    }
    int wave = threadIdx.x >> 6;
    int lane = threadIdx.x & 63;
    int row = blockIdx.x * 4 + wave;
    const float* hr = H + row * D_MODEL;
    float4 a = *(const float4*)&hr[lane * 4];
    float4 b = *(const float4*)&hr[256 + lane * 4];
    float sum = a.x + a.y + a.z + a.w + b.x + b.y + b.z + b.w;
    #pragma unroll
    for (int off = 32; off; off >>= 1) sum += __shfl_down(sum, off);
    sum = __shfl(sum, 0);
    float mu = sum * (1.f / 512.f);
    float vs = 0.f;
    vs += (a.x - mu) * (a.x - mu); vs += (a.y - mu) * (a.y - mu);
    vs += (a.z - mu) * (a.z - mu); vs += (a.w - mu) * (a.w - mu);
    vs += (b.x - mu) * (b.x - mu); vs += (b.y - mu) * (b.y - mu);
    vs += (b.z - mu) * (b.z - mu); vs += (b.w - mu) * (b.w - mu);
    #pragma unroll
    for (int off = 32; off; off >>= 1) vs += __shfl_down(vs, off);
    if (lane == 0) {
        float var = vs * (1.f / 512.f);
        stats[row] = make_float2(mu, 1.0f / sqrtf(var + 1e-5f));
    }
}

// ---------------- kernel 2: projection GEMM ----------------
// grid (64 row-tiles of 32, 8 k-chunks of 64); block 128 threads (2 waves).
// Thread (q8=tid&15 [q8<15 active for stores], rg=tid>>4): 4 rows x 8 cols register tile.
template <int ATOMIC>
__global__ __launch_bounds__(128) void proj_kernel(
    const float* __restrict__ H, const float2* __restrict__ stats,
    const float* __restrict__ lnw, const float* __restrict__ lnb,
    const float* __restrict__ Wp, float* __restrict__ Pout)
{
    __shared__ float Xt[64 * 32];      // [k][row] transposed, LN applied
    __shared__ float Ws[64 * WP_STRIDE]; // [k][c], zero-padded cols (flat copy of Wp chunk)
    int tid = threadIdx.x;
    int row0 = blockIdx.x * 32;
    int k0 = blockIdx.y * 64;

    {   // stage W chunk: flat float4 copy (strides match: both 128)
        const float4* Wp4 = (const float4*)(Wp + k0 * WP_STRIDE);
        float4* Ws4 = (float4*)Ws;
        #pragma unroll
        for (int i = 0; i < 16; ++i) Ws4[tid + i * 128] = Wp4[tid + i * 128];
    }
    {   // stage X transposed with LayerNorm
        int r = tid >> 2, fq = tid & 3;
        int row = row0 + r;
        float2 st = stats[row];
        const float4* H4 = (const float4*)(H + row * D_MODEL + k0);
        const float4* w4 = (const float4*)(lnw + k0);
        const float4* b4 = (const float4*)(lnb + k0);
        #pragma unroll
        for (int it = 0; it < 4; ++it) {
            int q = fq + it * 4;
            float4 h = H4[q], wv = w4[q], bv = b4[q];
            Xt[(4 * q + 0) * 32 + r] = (h.x - st.x) * st.y * wv.x + bv.x;
            Xt[(4 * q + 1) * 32 + r] = (h.y - st.x) * st.y * wv.y + bv.y;
            Xt[(4 * q + 2) * 32 + r] = (h.z - st.x) * st.y * wv.z + bv.z;
            Xt[(4 * q + 3) * 32 + r] = (h.w - st.x) * st.y * wv.w + bv.w;
        }
    }
    __syncthreads();

    int q8 = tid & 15;     // col group: cols 8*q8..8*q8+7 (q8=15 computes into pad)
    int rg = tid >> 4;     // row group: rows 4*rg..4*rg+3
    float acc[4][8];
    #pragma unroll
    for (int a = 0; a < 4; ++a)
        for (int u = 0; u < 8; ++u) acc[a][u] = 0.f;

    #pragma unroll 4
    for (int k = 0; k < 64; ++k) {
        float4 xa = *(float4*)&Xt[k * 32 + 4 * rg];
        float4 w0 = *(float4*)&Ws[k * WP_STRIDE + 8 * q8];
        float4 w1 = *(float4*)&Ws[k * WP_STRIDE + 8 * q8 + 4];
        float xv[4] = {xa.x, xa.y, xa.z, xa.w};
        float wv[8] = {w0.x, w0.y, w0.z, w0.w, w1.x, w1.y, w1.z, w1.w};
        #pragma unroll
        for (int a = 0; a < 4; ++a)
            #pragma unroll
            for (int u = 0; u < 8; ++u)
                acc[a][u] = fmaf(xv[a], wv[u], acc[a][u]);
    }

    if (q8 < 15) {
        float* Pk = ATOMIC ? Pout : (Pout + blockIdx.y * PCHUNK);
        #pragma unroll
        for (int a = 0; a < 4; ++a) {
            int row = row0 + 4 * rg + a;
            #pragma unroll
            for (int u = 0; u < 8; ++u) {
                int c = 8 * q8 + u;
                if (c < NCOL) {
                    if (ATOMIC) atomicAdd(&Pk[row * NCOL + c], acc[a][u]);
                    else        Pk[row * NCOL + c] = acc[a][u];
                }
            }
        }
    }
}

// ---------------- kernel 3: K-partial reduce + param transform + out init ----------------
// PARL/PARA: (c, -d/2*log2e, om/2pi, phi/2pi)
__global__ __launch_bounds__(256) void transform_kernel(
    const float* __restrict__ Pp, int nkc,
    const float* __restrict__ bias, const float* __restrict__ minp,
    float4* __restrict__ PARL, float4* __restrict__ PARA,
    float* __restrict__ out)
{
    int t = blockIdx.x * 256 + threadIdx.x;
    if (t >= S_LEN * NIMU) return;
    int s = t / NIMU;
    int m = t - s * NIMU;
    float pv[9];
    #pragma unroll
    for (int pp = 0; pp < 9; ++pp) {
        float v = bias[pp * NIMU + m];
        for (int kc = 0; kc < nkc; ++kc)
            v += Pp[kc * PCHUNK + s * NCOL + pp * NIMU + m];
        pv[pp] = v;
    }

    const float LOG2E = 1.4426950408889634f;
    const float INV2PI = 0.15915494309189535f;
    {   // linear oscillator
        float d = sqrtf(pv[1] * pv[1] + 1e-5f);
        float kk = d * d * 0.25f + softplus_f(pv[0]);
        float om = 0.5f * sqrtf(fmaxf(4.f * kk - d * d, 0.f));
        PARL[m * S_LEN + s] = make_float4(pv[4], -0.5f * d * LOG2E, om * INV2PI, pv[6] * INV2PI);
    }
    {   // angular oscillator
        float d = sqrtf(pv[3] * pv[3] + 1e-5f);
        float kk = d * d * 0.25f + softplus_f(pv[2]);
        float om = 0.5f * sqrtf(fmaxf(4.f * kk - d * d, 0.f));
        PARA[m * S_LEN + s] = make_float4(pv[5], -0.5f * d * LOG2E, om * INV2PI, pv[7] * INV2PI);
    }
    out[m * S_LEN + s] = minp[0] + pv[8];
}

// ---------------- kernel 4: triangular sum, per-wave LDS RMW ----------------
// grid (80, NIMU); block 256 = 4 waves. Anti-diagonal groups: all waves in a block
// share output window j in [64g, 64g+192). Wave tile: 64 sources x 128 dts.
// Tiles of group g: tc in [0, g/2], ic = g-2tc  (i0+dt0 = 64g for all).
__global__ __launch_bounds__(256) void main_kernel(
    const float4* __restrict__ PARL, const float4* __restrict__ PARA,
    float* __restrict__ out)
{
    __shared__ float buf[4 * 192];
    int tid = threadIdx.x;
    int lane = tid & 63, w = tid >> 6;
    int m = blockIdx.y;
    int bx = blockIdx.x;

    // decode bx -> (g, sub): group g has ceil((g/2+1)/4) blocks
    int g = 0, base = 0;
    #pragma unroll 1
    for (;;) {
        int nb = ((g >> 1) + 4) >> 2;
        if (bx < base + nb) break;
        base += nb; ++g;
    }
    int sub = bx - base;
    int q = sub * 4 + w;
    int gsize = (g >> 1) + 1;

    float* accW = buf + w * 192;
    accW[lane] = 0.f; accW[lane + 64] = 0.f; accW[lane + 128] = 0.f;
    __builtin_amdgcn_wave_barrier();

    if (q < gsize) {
        int tc = q;
        int ic = g - 2 * q;
        int i = ic * 64 + lane;
        float4 pl = PARL[m * S_LEN + i];
        float4 pa = PARA[m * S_LEN + i];
        // per-step rotation z = e^{-d/2} * (cos om, sin om)
        float ezL = __builtin_amdgcn_exp2f(pl.y);
        float zxL = ezL * __builtin_amdgcn_cosf(pl.z);
        float zyL = ezL * __builtin_amdgcn_sinf(pl.z);
        float ezA = __builtin_amdgcn_exp2f(pa.y);
        float zxA = ezA * __builtin_amdgcn_cosf(pa.z);
        float zyA = ezA * __builtin_amdgcn_sinf(pa.z);
        // init state at dt0 = 128*tc
        float dtf = (float)(tc * 128);
        float reL, imL, reA, imA;
        {
            float er = pl.x * __builtin_amdgcn_exp2f(dtf * pl.y);
            float r = fmaf(dtf, pl.z, pl.w); r -= floorf(r);
            reL = er * __builtin_amdgcn_cosf(r);
            imL = er * __builtin_amdgcn_sinf(r);
        }
        {
            float er = pa.x * __builtin_amdgcn_exp2f(dtf * pa.y);
            float r = fmaf(dtf, pa.z, pa.w); r -= floorf(r);
            reA = er * __builtin_amdgcn_cosf(r);
            imA = er * __builtin_amdgcn_sinf(r);
        }
        #pragma unroll 4
        for (int t = 0; t < 128; ++t) {
            // slot lane+t: cross-lane RMW chain; wave-lockstep + in-order LDS
            accW[lane + t] += imL + imA;
            __builtin_amdgcn_wave_barrier();   // pin compiler ordering of LDS RMWs
            float nL = fmaf(reL, zxL, -(imL * zyL));
            imL = fmaf(reL, zyL, imL * zxL);
            reL = nL;
            float nA = fmaf(reA, zxA, -(imA * zyA));
            imA = fmaf(reA, zyA, imA * zxA);
            reA = nA;
        }
    }
    __syncthreads();
    if (tid < 192) {
        float s = buf[tid] + buf[192 + tid] + buf[384 + tid] + buf[576 + tid];
        int j = g * 64 + tid;
        if (j < S_LEN) atomicAdd(&out[m * S_LEN + j], s);
    }
}

extern "C" void kernel_launch(void* const* d_in, const int* in_sizes, int n_in,
                              void* d_out, int out_size, void* d_ws, size_t ws_size,
                              hipStream_t stream)
{
    const float* H    = (const float*)d_in[0];
    const float* MINP = (const float*)d_in[1];
    const float* LNW  = (const float*)d_in[2];
    const float* LNB  = (const float*)d_in[3];
    const float* W    = (const float*)d_in[4];
    const float* B    = (const float*)d_in[5];
    float* out = (float*)d_out;

    const size_t PSZ   = (size_t)PCHUNK * sizeof(float);        // 958464
    const size_t STSZ  = S_LEN * sizeof(float2);                // 16384
    const size_t PARSZ = (size_t)S_LEN * NIMU * sizeof(float4); // 425984
    const size_t need8 = 8 * PSZ + STSZ + 2 * PARSZ;            // 8536064 (proven ws floor)

    char* ws = (char*)d_ws;
    if (ws_size >= need8) {
        float*  Pp    = (float*)ws;
        float2* stats = (float2*)(ws + 8 * PSZ);
        float4* PARL  = (float4*)(ws + 8 * PSZ + STSZ);
        float4* PARA  = (float4*)(ws + 8 * PSZ + STSZ + PARSZ);
        float*  Wp    = (float*)PARL;   // alias: Wp dead before PARL is written
        stats_kernel<<<512, 256, 0, stream>>>(H, stats, W, Wp);
        proj_kernel<0><<<dim3(64, 8), 128, 0, stream>>>(H, stats, LNW, LNB, Wp, Pp);
        transform_kernel<<<(S_LEN * NIMU + 255) / 256, 256, 0, stream>>>(Pp, 8, B, MINP, PARL, PARA, out);
        main_kernel<<<dim3(80, NIMU), 256, 0, stream>>>(PARL, PARA, out);
    } else {
        float*  P     = (float*)ws;
        float2* stats = (float2*)(ws + PSZ);
        float4* PARL  = (float4*)(ws + PSZ + STSZ);
        float4* PARA  = (float4*)(ws + PSZ + STSZ + PARSZ);
        float*  Wp    = (float*)PARL;
        hipMemsetAsync(P, 0, PSZ, stream);
        stats_kernel<<<512, 256, 0, stream>>>(H, stats, W, Wp);
        proj_kernel<1><<<dim3(64, 8), 128, 0, stream>>>(H, stats, LNW, LNB, Wp, P);
        transform_kernel<<<(S_LEN * NIMU + 255) / 256, 256, 0, stream>>>(P, 1, B, MINP, PARL, PARA, out);
        main_kernel<<<dim3(80, NIMU), 256, 0, stream>>>(PARL, PARA, out);
    }
}

// Round 5
// 99.169 us; speedup vs baseline: 2.4580x; 1.1309x over previous
//
#include <hip/hip_runtime.h>
#include <math.h>

#define S_LEN 2048
#define D_MODEL 512
#define NIMU 13
#define NCOL 117                 // 13*9
#define CPAD 128                 // padded col stride
#define NKC 8                    // k-split chunks
// Pt[kc][c][s] = Pt[(kc*CPAD + c)*S_LEN + s]
#define KCSTRIDE ((size_t)CPAD * S_LEN)

static __device__ __forceinline__ float softplus_f(float x) {
    return (x > 20.f) ? x : log1pf(expf(x));
}

// osc transform: params -> per-step rotation z and state at dt0
static __device__ __forceinline__ void osc_init(float pk, float pd, float amp, float phi, float dtf,
                                                float& re, float& im, float& zr, float& zi)
{
    const float LOG2E = 1.4426950408889634f;
    const float INV2PI = 0.15915494309189535f;
    float d = sqrtf(pd * pd + 1e-5f);
    float kk = d * d * 0.25f + softplus_f(pk);
    float om = 0.5f * sqrtf(fmaxf(4.f * kk - d * d, 0.f));
    float y = -0.5f * d * LOG2E;       // log2 of decay per step
    float f = om * INV2PI;             // revolutions per step
    float ph = phi * INV2PI;
    float ez = __builtin_amdgcn_exp2f(y);
    zr = ez * __builtin_amdgcn_cosf(f);
    zi = ez * __builtin_amdgcn_sinf(f);
    float er = amp * __builtin_amdgcn_exp2f(dtf * y);
    float r = fmaf(dtf, f, ph); r -= floorf(r);
    re = er * __builtin_amdgcn_cosf(r);
    im = er * __builtin_amdgcn_sinf(r);
}

// ---------------- kernel 1: LN stats + W pad + out zero ----------------
// 512 blocks x 256. Block bx: rows 4bx..4bx+3 stats; pads W row bx into Wp; zeroes out.
__global__ __launch_bounds__(256) void stats_kernel(const float* __restrict__ H,
                                                    float2* __restrict__ stats,
                                                    const float* __restrict__ W,
                                                    float* __restrict__ Wp,
                                                    float* __restrict__ out) {
    if (blockIdx.x < 104) out[blockIdx.x * 256 + threadIdx.x] = 0.f;   // 104*256 = 26624 = 13*2048
    if (threadIdx.x < CPAD) {
        int c = threadIdx.x;
        Wp[blockIdx.x * CPAD + c] = (c < NCOL) ? W[blockIdx.x * NCOL + c] : 0.f;
    }
    int wave = threadIdx.x >> 6;
    int lane = threadIdx.x & 63;
    int row = blockIdx.x * 4 + wave;
    const float* hr = H + row * D_MODEL;
    float4 a = *(const float4*)&hr[lane * 4];
    float4 b = *(const float4*)&hr[256 + lane * 4];
    float sum = a.x + a.y + a.z + a.w + b.x + b.y + b.z + b.w;
    #pragma unroll
    for (int off = 32; off; off >>= 1) sum += __shfl_down(sum, off);
    sum = __shfl(sum, 0);
    float mu = sum * (1.f / 512.f);
    float vs = 0.f;
    vs += (a.x - mu) * (a.x - mu); vs += (a.y - mu) * (a.y - mu);
    vs += (a.z - mu) * (a.z - mu); vs += (a.w - mu) * (a.w - mu);
    vs += (b.x - mu) * (b.x - mu); vs += (b.y - mu) * (b.y - mu);
    vs += (b.z - mu) * (b.z - mu); vs += (b.w - mu) * (b.w - mu);
    #pragma unroll
    for (int off = 32; off; off >>= 1) vs += __shfl_down(vs, off);
    if (lane == 0) {
        float var = vs * (1.f / 512.f);
        stats[row] = make_float2(mu, 1.0f / sqrtf(var + 1e-5f));
    }
}

// ---------------- kernel 2: projection GEMM -> transposed partials ----------------
// grid (64 row-tiles of 32, 8 k-chunks of 64); block 128 threads.
__global__ __launch_bounds__(128) void proj_kernel(
    const float* __restrict__ H, const float2* __restrict__ stats,
    const float* __restrict__ lnw, const float* __restrict__ lnb,
    const float* __restrict__ Wp, float* __restrict__ Pt)
{
    __shared__ float Xt[64 * 32];        // [k][row] transposed, LN applied
    __shared__ float Ws[64 * CPAD];      // [k][c]
    int tid = threadIdx.x;
    int row0 = blockIdx.x * 32;
    int k0 = blockIdx.y * 64;

    {   // stage W chunk: flat float4 copy (strides match: both 128)
        const float4* Wp4 = (const float4*)(Wp + k0 * CPAD);
        float4* Ws4 = (float4*)Ws;
        #pragma unroll
        for (int i = 0; i < 16; ++i) Ws4[tid + i * 128] = Wp4[tid + i * 128];
    }
    {   // stage X transposed with LayerNorm
        int r = tid >> 2, fq = tid & 3;
        int row = row0 + r;
        float2 st = stats[row];
        const float4* H4 = (const float4*)(H + row * D_MODEL + k0);
        const float4* w4 = (const float4*)(lnw + k0);
        const float4* b4 = (const float4*)(lnb + k0);
        #pragma unroll
        for (int it = 0; it < 4; ++it) {
            int q = fq + it * 4;
            float4 h = H4[q], wv = w4[q], bv = b4[q];
            Xt[(4 * q + 0) * 32 + r] = (h.x - st.x) * st.y * wv.x + bv.x;
            Xt[(4 * q + 1) * 32 + r] = (h.y - st.x) * st.y * wv.y + bv.y;
            Xt[(4 * q + 2) * 32 + r] = (h.z - st.x) * st.y * wv.z + bv.z;
            Xt[(4 * q + 3) * 32 + r] = (h.w - st.x) * st.y * wv.w + bv.w;
        }
    }
    __syncthreads();

    int q8 = tid & 15;     // col group: cols 8*q8..8*q8+7
    int rg = tid >> 4;     // row group: rows 4*rg..4*rg+3
    float acc[4][8];
    #pragma unroll
    for (int a = 0; a < 4; ++a)
        for (int u = 0; u < 8; ++u) acc[a][u] = 0.f;

    #pragma unroll 4
    for (int k = 0; k < 64; ++k) {
        float4 xa = *(float4*)&Xt[k * 32 + 4 * rg];
        float4 w0 = *(float4*)&Ws[k * CPAD + 8 * q8];
        float4 w1 = *(float4*)&Ws[k * CPAD + 8 * q8 + 4];
        float xv[4] = {xa.x, xa.y, xa.z, xa.w};
        float wv[8] = {w0.x, w0.y, w0.z, w0.w, w1.x, w1.y, w1.z, w1.w};
        #pragma unroll
        for (int a = 0; a < 4; ++a)
            #pragma unroll
            for (int u = 0; u < 8; ++u)
                acc[a][u] = fmaf(xv[a], wv[u], acc[a][u]);
    }

    if (q8 < 15) {
        #pragma unroll
        for (int u = 0; u < 8; ++u) {
            int c = 8 * q8 + u;
            if (c < NCOL) {
                float4 v = make_float4(acc[0][u], acc[1][u], acc[2][u], acc[3][u]);
                *(float4*)&Pt[((size_t)blockIdx.y * CPAD + c) * S_LEN + row0 + 4 * rg] = v;
            }
        }
    }
}

// ---------------- kernel 3: inline transform + triangular recurrence + init ----------------
// grid (40, NIMU); block 256 = 4 waves. Wave-tile: 128 sources x 128 dts.
// Group g = sc+tc in [0,16): g+1 tiles, window j in [128g, 128g+255].
// Lane owns sources i0+lane (slot lane+t) and i0+64+lane (slot lane+64+t), both at dt=t.
__global__ __launch_bounds__(256) void main_kernel(
    const float* __restrict__ Pt, const float* __restrict__ bias,
    const float* __restrict__ minp, float* __restrict__ out)
{
    __shared__ float buf[4 * 256];
    int tid = threadIdx.x;
    int lane = tid & 63, w = tid >> 6;
    int m = blockIdx.y;
    int bx = blockIdx.x;

    // decode bx -> (g, sub): group g has ceil((g+1)/4) = (g+4)>>2 blocks
    int g = 0, base = 0;
    #pragma unroll 1
    for (;;) {
        int nb = (g + 4) >> 2;
        if (bx < base + nb) break;
        base += nb; ++g;
    }
    int sub = bx - base;
    int q = sub * 4 + w;               // tile index within group

    float* accW = buf + w * 256;
    accW[lane] = 0.f; accW[lane + 64] = 0.f;
    accW[lane + 128] = 0.f; accW[lane + 192] = 0.f;
    __builtin_amdgcn_wave_barrier();

    if (q <= g) {
        int sc = q, tc = g - q;
        int i0 = sc * 128;
        float dtf = (float)(tc * 128);

        // gather 9 params for sources A = i0+lane, B = i0+64+lane (coalesced b32)
        float pvA[9], pvB[9];
        #pragma unroll
        for (int p = 0; p < 9; ++p) {
            int c = p * 13 + m;
            const float* bp = Pt + (size_t)c * S_LEN + i0 + lane;
            float vA = bias[c], vB = vA;
            #pragma unroll
            for (int kc = 0; kc < NKC; ++kc) {
                vA += bp[kc * KCSTRIDE];
                vB += bp[kc * KCSTRIDE + 64];
            }
            pvA[p] = vA; pvB[p] = vB;
        }

        float reLA, imLA, zrLA, ziLA; osc_init(pvA[0], pvA[1], pvA[4], pvA[6], dtf, reLA, imLA, zrLA, ziLA);
        float reAA, imAA, zrAA, ziAA; osc_init(pvA[2], pvA[3], pvA[5], pvA[7], dtf, reAA, imAA, zrAA, ziAA);
        float reLB, imLB, zrLB, ziLB; osc_init(pvB[0], pvB[1], pvB[4], pvB[6], dtf, reLB, imLB, zrLB, ziLB);
        float reAB, imAB, zrAB, ziAB; osc_init(pvB[2], pvB[3], pvB[5], pvB[7], dtf, reAB, imAB, zrAB, ziAB);

        #pragma unroll 8
        for (int t = 0; t < 128; ++t) {
            // paired slots (lane+t, lane+64+t): stride-1 across lanes, read2/write2-eligible
            float a0 = accW[lane + t];
            float a1 = accW[lane + 64 + t];
            a0 += imLA + imAA;
            a1 += imLB + imAB;
            accW[lane + t] = a0;
            accW[lane + 64 + t] = a1;
            __builtin_amdgcn_wave_barrier();   // pin cross-lane LDS RMW ordering
            float tL = imLA * ziLA; float rL = fmaf(reLA, zrLA, -tL);
            imLA = fmaf(reLA, ziLA, imLA * zrLA); reLA = rL;
            float tA = imAA * ziAA; float rA = fmaf(reAA, zrAA, -tA);
            imAA = fmaf(reAA, ziAA, imAA * zrAA); reAA = rA;
            float tLB = imLB * ziLB; float rLB = fmaf(reLB, zrLB, -tLB);
            imLB = fmaf(reLB, ziLB, imLB * zrLB); reLB = rLB;
            float tAB = imAB * ziAB; float rAB = fmaf(reAB, zrAB, -tAB);
            imAB = fmaf(reAB, ziAB, imAB * zrAB); reAB = rAB;
        }
    }
    __syncthreads();

    // flush: window j in [128g, 128g+256)
    {
        int j = g * 128 + tid;
        if (j < S_LEN) {
            float s = buf[tid] + buf[256 + tid] + buf[512 + tid] + buf[768 + tid];
            if (sub == 0 && tid < 128) {
                // exactly-once init for j in [128g, 128g+128): minp + p8
                int c8 = 8 * 13 + m;
                float v = minp[0] + bias[c8];
                const float* bp = Pt + (size_t)c8 * S_LEN + j;
                #pragma unroll
                for (int kc = 0; kc < NKC; ++kc) v += bp[kc * KCSTRIDE];
                s += v;
            }
            atomicAdd(&out[m * S_LEN + j], s);
        }
    }
}

extern "C" void kernel_launch(void* const* d_in, const int* in_sizes, int n_in,
                              void* d_out, int out_size, void* d_ws, size_t ws_size,
                              hipStream_t stream)
{
    const float* H    = (const float*)d_in[0];
    const float* MINP = (const float*)d_in[1];
    const float* LNW  = (const float*)d_in[2];
    const float* LNB  = (const float*)d_in[3];
    const float* W    = (const float*)d_in[4];
    const float* B    = (const float*)d_in[5];
    float* out = (float*)d_out;

    const size_t PTSZ = (size_t)NKC * CPAD * S_LEN * sizeof(float);  // 8388608
    const size_t STSZ = S_LEN * sizeof(float2);                      // 16384

    char* ws = (char*)d_ws;
    float*  Pt    = (float*)ws;
    float2* stats = (float2*)(ws + PTSZ);
    float*  Wp    = (float*)(ws + PTSZ + STSZ);                      // 512*128*4 = 262144

    stats_kernel<<<512, 256, 0, stream>>>(H, stats, W, Wp, out);
    proj_kernel<<<dim3(64, 8), 128, 0, stream>>>(H, stats, LNW, LNB, Wp, Pt);
    main_kernel<<<dim3(40, NIMU), 256, 0, stream>>>(Pt, B, MINP, out);
}